// Round 1
// baseline (562.762 us; speedup 1.0000x reference)
//
#include <hip/hip_runtime.h>
#include <hip/hip_bf16.h>

#define NB 4
#define NT 2048
#define NC 1024
#define NH 16
#define ND 64
#define BT (NB*NT)

typedef __attribute__((ext_vector_type(8))) short bf16x8;
typedef __attribute__((ext_vector_type(4))) float f32x4;

static __device__ __forceinline__ short f2bf(float f) {
    union { float f; unsigned u; } v; v.f = f;
    unsigned r = (v.u + 0x7fffu + ((v.u >> 16) & 1u)) >> 16;
    return (short)r;
}

static __device__ __forceinline__ f32x4 mfma16(bf16x8 a, bf16x8 b, f32x4 c) {
    return __builtin_amdgcn_mfma_f32_16x16x32_bf16(a, b, c, 0, 0, 0);
}

// ---------------------------------------------------------------------------
// GEMM1: qkv = x @ w_qkv + b_qkv ; scatter to q (scaled 1/8), k, v^T (bf16)
// x fp32 [BT][NC], w fp32 [NC][3NC]. 128x128 tile, BK=32, 4 waves (2x2).
// ---------------------------------------------------------------------------
__global__ __launch_bounds__(256)
void qkv_gemm(const float* __restrict__ x, const float* __restrict__ w,
              const float* __restrict__ bias,
              short* __restrict__ q, short* __restrict__ k, short* __restrict__ vt)
{
    __shared__ short aLds[128][40];  // [m][k], pad 32->40
    __shared__ short bLds[128][40];  // [n][k] transposed, pad 32->40
    const int tid  = threadIdx.x;
    const int lane = tid & 63;
    const int wave = tid >> 6;
    const int waveM = wave & 1;
    const int waveN = wave >> 1;
    const int quad = lane >> 4;
    const int l15  = lane & 15;
    const int m0 = blockIdx.x * 128;
    const int n0 = blockIdx.y * 128;

    f32x4 acc[4][4];
#pragma unroll
    for (int i = 0; i < 4; ++i)
#pragma unroll
        for (int j = 0; j < 4; ++j) acc[i][j] = 0.0f;

    const int arow = tid >> 1;
    const int acb  = (tid & 1) << 4;
    const int bn   = tid & 127;
    const int bkb  = (tid >> 7) << 4;

    for (int k0 = 0; k0 < NC; k0 += 32) {
        // stage A (fp32 -> bf16): 128x32
        {
            const float* src = x + (size_t)(m0 + arow) * NC + k0 + acb;
            float4 f0 = *(const float4*)(src + 0);
            float4 f1 = *(const float4*)(src + 4);
            float4 f2 = *(const float4*)(src + 8);
            float4 f3 = *(const float4*)(src + 12);
            bf16x8 p0, p1;
            p0[0]=f2bf(f0.x); p0[1]=f2bf(f0.y); p0[2]=f2bf(f0.z); p0[3]=f2bf(f0.w);
            p0[4]=f2bf(f1.x); p0[5]=f2bf(f1.y); p0[6]=f2bf(f1.z); p0[7]=f2bf(f1.w);
            p1[0]=f2bf(f2.x); p1[1]=f2bf(f2.y); p1[2]=f2bf(f2.z); p1[3]=f2bf(f2.w);
            p1[4]=f2bf(f3.x); p1[5]=f2bf(f3.y); p1[6]=f2bf(f3.z); p1[7]=f2bf(f3.w);
            *(bf16x8*)&aLds[arow][acb]     = p0;
            *(bf16x8*)&aLds[arow][acb + 8] = p1;
        }
        // stage B transposed: tile rows k0..k0+31 of w, cols n0..n0+127
        {
            const float* src = w + (size_t)(k0 + bkb) * (3*NC) + n0 + bn;
            short t16[16];
#pragma unroll
            for (int kk = 0; kk < 16; ++kk) t16[kk] = f2bf(src[(size_t)kk * (3*NC)]);
            bf16x8 p0, p1;
#pragma unroll
            for (int j = 0; j < 8; ++j) { p0[j] = t16[j]; p1[j] = t16[8 + j]; }
            *(bf16x8*)&bLds[bn][bkb]     = p0;
            *(bf16x8*)&bLds[bn][bkb + 8] = p1;
        }
        __syncthreads();

        bf16x8 af[4], bfr[4];
#pragma unroll
        for (int mi = 0; mi < 4; ++mi)
            af[mi] = *(const bf16x8*)&aLds[waveM*64 + mi*16 + l15][quad*8];
#pragma unroll
        for (int ni = 0; ni < 4; ++ni)
            bfr[ni] = *(const bf16x8*)&bLds[waveN*64 + ni*16 + l15][quad*8];
#pragma unroll
        for (int mi = 0; mi < 4; ++mi)
#pragma unroll
            for (int ni = 0; ni < 4; ++ni)
                acc[mi][ni] = mfma16(af[mi], bfr[ni], acc[mi][ni]);
        __syncthreads();
    }

    // epilogue: bias, scatter to q/k/vt (bf16). n layout: s*1024 + h*64 + d
#pragma unroll
    for (int mi = 0; mi < 4; ++mi) {
#pragma unroll
        for (int ni = 0; ni < 4; ++ni) {
            const int n = n0 + waveN*64 + ni*16 + l15;
            const float bb = bias[n];
            const int s = n >> 10;
            const int h = (n >> 6) & 15;
            const int d = n & 63;
#pragma unroll
            for (int r = 0; r < 4; ++r) {
                const int m = m0 + waveM*64 + mi*16 + quad*4 + r;
                const int b = m >> 11;
                const int t = m & (NT - 1);
                const float val = acc[mi][ni][r] + bb;
                const size_t bhx = (size_t)(b * NH + h);
                if (s == 0)      q [(bhx * NT + t) * ND + d] = f2bf(val * 0.125f);
                else if (s == 1) k [(bhx * NT + t) * ND + d] = f2bf(val);
                else             vt[(bhx * ND + d) * NT + t] = f2bf(val);
            }
        }
    }
}

// ---------------------------------------------------------------------------
// Flash attention, causal. Block = 128 q-rows (4 waves x 32), key tiles of 32.
// q pre-scaled by 1/sqrt(D). vt is [BH][D][T]. ctx out bf16 [B][T][C].
// ---------------------------------------------------------------------------
__global__ __launch_bounds__(256)
void attn(const short* __restrict__ q, const short* __restrict__ k,
          const short* __restrict__ vt, short* __restrict__ ctx)
{
    __shared__ short kLds[32][72];      // [key][d] pad 64->72
    __shared__ short vLds[64][40];      // [d][key] pad 32->40
    __shared__ short pLds[4][32][40];   // per-wave P [row][key] pad 32->40
    const int tid  = threadIdx.x;
    const int lane = tid & 63;
    const int wave = tid >> 6;
    const int quad = lane >> 4;
    const int l15  = lane & 15;
    const int qb = blockIdx.x * 128;
    const int bh = blockIdx.y;
    const int b  = bh >> 4;
    const int h  = bh & 15;

    const short* Qp = q  + (size_t)bh * NT * ND;
    const short* Kp = k  + (size_t)bh * NT * ND;
    const short* Vp = vt + (size_t)bh * ND * NT;

    const int wq0 = qb + wave * 32;

    // Q fragments (A layout), one-time global read
    bf16x8 qf[2][2];
#pragma unroll
    for (int mi = 0; mi < 2; ++mi)
#pragma unroll
        for (int kd = 0; kd < 2; ++kd)
            qf[mi][kd] = *(const bf16x8*)(Qp + (size_t)(wq0 + mi*16 + l15) * ND + kd*32 + quad*8);

    f32x4 o[2][4];
    float mr[2][4], lr[2][4];
#pragma unroll
    for (int mi = 0; mi < 2; ++mi) {
#pragma unroll
        for (int di = 0; di < 4; ++di) o[mi][di] = 0.0f;
#pragma unroll
        for (int r = 0; r < 4; ++r) { mr[mi][r] = -__builtin_inff(); lr[mi][r] = 0.0f; }
    }

    const int ktiles = (qb + 128) >> 5;
    const int krow = tid >> 3, kcb = (tid & 7) << 3;   // K stage: 32x64
    const int vrow = tid >> 2, vcb = (tid & 3) << 3;   // V stage: 64x32

    for (int kt = 0; kt < ktiles; ++kt) {
        const int kb = kt << 5;
        __syncthreads();   // previous tile's LDS reads done
        *(bf16x8*)&kLds[krow][kcb] = *(const bf16x8*)(Kp + (size_t)(kb + krow) * ND + kcb);
        *(bf16x8*)&vLds[vrow][vcb] = *(const bf16x8*)(Vp + (size_t)vrow * NT + kb + vcb);
        __syncthreads();

        // S = Q K^T  (keys 32, split into 2 n-tiles of 16; K-dim 64 = 2 MFMAs)
        bf16x8 kf[2][2];
#pragma unroll
        for (int ni = 0; ni < 2; ++ni)
#pragma unroll
            for (int kd = 0; kd < 2; ++kd)
                kf[ni][kd] = *(const bf16x8*)&kLds[ni*16 + l15][kd*32 + quad*8];

        f32x4 s[2][2];
#pragma unroll
        for (int mi = 0; mi < 2; ++mi)
#pragma unroll
            for (int ni = 0; ni < 2; ++ni) {
                s[mi][ni] = 0.0f;
                s[mi][ni] = mfma16(qf[mi][0], kf[ni][0], s[mi][ni]);
                s[mi][ni] = mfma16(qf[mi][1], kf[ni][1], s[mi][ni]);
            }

        // causal mask (only needed near the diagonal of this wave)
        if (kb + 31 > wq0) {
#pragma unroll
            for (int mi = 0; mi < 2; ++mi)
#pragma unroll
                for (int ni = 0; ni < 2; ++ni)
#pragma unroll
                    for (int r = 0; r < 4; ++r) {
                        const int qrow = wq0 + mi*16 + quad*4 + r;
                        const int key  = kb + ni*16 + l15;
                        if (key > qrow) s[mi][ni][r] = -__builtin_inff();
                    }
        }

        // online softmax (rows live at quad*4+r; reduce across the 16 lanes of a quad)
#pragma unroll
        for (int mi = 0; mi < 2; ++mi) {
            float nm[4], al[4], rs[4];
#pragma unroll
            for (int r = 0; r < 4; ++r) nm[r] = fmaxf(s[mi][0][r], s[mi][1][r]);
#pragma unroll
            for (int off = 1; off < 16; off <<= 1)
#pragma unroll
                for (int r = 0; r < 4; ++r) nm[r] = fmaxf(nm[r], __shfl_xor(nm[r], off));
#pragma unroll
            for (int r = 0; r < 4; ++r) {
                const float mnew = fmaxf(mr[mi][r], nm[r]);
                al[r] = __expf(mr[mi][r] - mnew);
                mr[mi][r] = mnew;
                rs[r] = 0.0f;
            }
#pragma unroll
            for (int ni = 0; ni < 2; ++ni)
#pragma unroll
                for (int r = 0; r < 4; ++r) {
                    const float e = __expf(s[mi][ni][r] - mr[mi][r]);
                    s[mi][ni][r] = e;
                    rs[r] += e;
                }
#pragma unroll
            for (int off = 1; off < 16; off <<= 1)
#pragma unroll
                for (int r = 0; r < 4; ++r) rs[r] += __shfl_xor(rs[r], off);
#pragma unroll
            for (int r = 0; r < 4; ++r) lr[mi][r] = lr[mi][r] * al[r] + rs[r];
#pragma unroll
            for (int di = 0; di < 4; ++di)
#pragma unroll
                for (int r = 0; r < 4; ++r) o[mi][di][r] *= al[r];
            // P (C layout) -> LDS for A-layout reload
#pragma unroll
            for (int ni = 0; ni < 2; ++ni)
#pragma unroll
                for (int r = 0; r < 4; ++r)
                    pLds[wave][mi*16 + quad*4 + r][ni*16 + l15] = f2bf(s[mi][ni][r]);
        }
        __syncthreads();

        // PV: P(32x32) @ V(32x64)
        bf16x8 pf[2], vf[4];
#pragma unroll
        for (int mi = 0; mi < 2; ++mi)
            pf[mi] = *(const bf16x8*)&pLds[wave][mi*16 + l15][quad*8];
#pragma unroll
        for (int di = 0; di < 4; ++di)
            vf[di] = *(const bf16x8*)&vLds[di*16 + l15][quad*8];
#pragma unroll
        for (int mi = 0; mi < 2; ++mi)
#pragma unroll
            for (int di = 0; di < 4; ++di)
                o[mi][di] = mfma16(pf[mi], vf[di], o[mi][di]);
    }

    // epilogue: ctx[b][t][h*64+d] = o / l
#pragma unroll
    for (int mi = 0; mi < 2; ++mi)
#pragma unroll
        for (int di = 0; di < 4; ++di)
#pragma unroll
            for (int r = 0; r < 4; ++r) {
                const int t = wq0 + mi*16 + quad*4 + r;
                const float val = o[mi][di][r] / lr[mi][r];
                ctx[((size_t)(b * NT + t)) * NC + h*64 + di*16 + l15] = f2bf(val);
            }
}

// ---------------------------------------------------------------------------
// GEMM2: out = ctx @ w_out + b_out (fp32 out). ctx bf16 [BT][NC], w fp32 [NC][NC]
// ---------------------------------------------------------------------------
__global__ __launch_bounds__(256)
void out_gemm(const short* __restrict__ a, const float* __restrict__ w,
              const float* __restrict__ bias, float* __restrict__ out)
{
    __shared__ short aLds[128][40];
    __shared__ short bLds[128][40];
    const int tid  = threadIdx.x;
    const int lane = tid & 63;
    const int wave = tid >> 6;
    const int waveM = wave & 1;
    const int waveN = wave >> 1;
    const int quad = lane >> 4;
    const int l15  = lane & 15;
    const int m0 = blockIdx.x * 128;
    const int n0 = blockIdx.y * 128;

    f32x4 acc[4][4];
#pragma unroll
    for (int i = 0; i < 4; ++i)
#pragma unroll
        for (int j = 0; j < 4; ++j) acc[i][j] = 0.0f;

    const int arow = tid >> 1;
    const int acb  = (tid & 1) << 4;
    const int bn   = tid & 127;
    const int bkb  = (tid >> 7) << 4;

    for (int k0 = 0; k0 < NC; k0 += 32) {
        {
            const short* src = a + (size_t)(m0 + arow) * NC + k0 + acb;
            *(bf16x8*)&aLds[arow][acb]     = *(const bf16x8*)src;
            *(bf16x8*)&aLds[arow][acb + 8] = *(const bf16x8*)(src + 8);
        }
        {
            const float* src = w + (size_t)(k0 + bkb) * NC + n0 + bn;
            short t16[16];
#pragma unroll
            for (int kk = 0; kk < 16; ++kk) t16[kk] = f2bf(src[(size_t)kk * NC]);
            bf16x8 p0, p1;
#pragma unroll
            for (int j = 0; j < 8; ++j) { p0[j] = t16[j]; p1[j] = t16[8 + j]; }
            *(bf16x8*)&bLds[bn][bkb]     = p0;
            *(bf16x8*)&bLds[bn][bkb + 8] = p1;
        }
        __syncthreads();

        bf16x8 af[4], bfr[4];
#pragma unroll
        for (int mi = 0; mi < 4; ++mi)
            af[mi] = *(const bf16x8*)&aLds[waveM*64 + mi*16 + l15][quad*8];
#pragma unroll
        for (int ni = 0; ni < 4; ++ni)
            bfr[ni] = *(const bf16x8*)&bLds[waveN*64 + ni*16 + l15][quad*8];
#pragma unroll
        for (int mi = 0; mi < 4; ++mi)
#pragma unroll
            for (int ni = 0; ni < 4; ++ni)
                acc[mi][ni] = mfma16(af[mi], bfr[ni], acc[mi][ni]);
        __syncthreads();
    }

#pragma unroll
    for (int mi = 0; mi < 4; ++mi) {
#pragma unroll
        for (int ni = 0; ni < 4; ++ni) {
            const int n = n0 + waveN*64 + ni*16 + l15;
            const float bb = bias[n];
#pragma unroll
            for (int r = 0; r < 4; ++r) {
                const int m = m0 + waveM*64 + mi*16 + quad*4 + r;
                out[(size_t)m * NC + n] = acc[mi][ni][r] + bb;
            }
        }
    }
}

extern "C" void kernel_launch(void* const* d_in, const int* in_sizes, int n_in,
                              void* d_out, int out_size, void* d_ws, size_t ws_size,
                              hipStream_t stream)
{
    const float* x     = (const float*)d_in[0];
    const float* w_qkv = (const float*)d_in[1];
    const float* b_qkv = (const float*)d_in[2];
    const float* w_out = (const float*)d_in[3];
    const float* b_out = (const float*)d_in[4];
    float* out = (float*)d_out;

    const size_t SZ = (size_t)NB * NH * NT * ND;   // 8,388,608 elems (16 MB bf16)
    short* q   = (short*)d_ws;
    short* kk  = q  + SZ;
    short* vt  = kk + SZ;
    short* ctx = vt + SZ;

    hipLaunchKernelGGL(qkv_gemm, dim3(BT/128, (3*NC)/128), dim3(256), 0, stream,
                       x, w_qkv, b_qkv, q, kk, vt);
    hipLaunchKernelGGL(attn, dim3(NT/128, NB*NH), dim3(256), 0, stream,
                       q, kk, vt, ctx);
    hipLaunchKernelGGL(out_gemm, dim3(BT/128, NC/128), dim3(256), 0, stream,
                       ctx, w_out, b_out, out);
}

// Round 2
// 401.218 us; speedup vs baseline: 1.4026x; 1.4026x over previous
//
#include <hip/hip_runtime.h>
#include <hip/hip_bf16.h>

#define NB 4
#define NT 2048
#define NC 1024
#define NH 16
#define ND 64
#define BT (NB*NT)
#define LOG2E 1.4426950408889634f
#define NEG_BIG (-3.0e38f)

typedef __attribute__((ext_vector_type(8))) short bf16x8;
typedef __attribute__((ext_vector_type(4))) float f32x4;

static __device__ __forceinline__ short f2bf(float f) {
    union { float f; unsigned u; } v; v.f = f;
    unsigned r = (v.u + 0x7fffu + ((v.u >> 16) & 1u)) >> 16;
    return (short)r;
}

static __device__ __forceinline__ f32x4 mfma16(bf16x8 a, bf16x8 b, f32x4 c) {
    return __builtin_amdgcn_mfma_f32_16x16x32_bf16(a, b, c, 0, 0, 0);
}

static __device__ __forceinline__ float fexp2(float x) {
#if __has_builtin(__builtin_amdgcn_exp2f)
    return __builtin_amdgcn_exp2f(x);
#else
    return exp2f(x);
#endif
}

// ---------------------------------------------------------------------------
// Transpose + convert: w fp32 [R][Cn] -> wt bf16 [Cn][R]. 64x64 tiles.
// ---------------------------------------------------------------------------
__global__ __launch_bounds__(256)
void transpose_w(const float* __restrict__ w, short* __restrict__ wt, int R, int Cn)
{
    __shared__ short t[64][72];
    const int tid = threadIdx.x;
    const int r0 = blockIdx.x * 64;
    const int c0 = blockIdx.y * 64;
    {
        const int rl = tid >> 2, c4 = (tid & 3) << 4;
        const float* src = w + (size_t)(r0 + rl) * Cn + c0 + c4;
        float4 f0 = *(const float4*)(src + 0);
        float4 f1 = *(const float4*)(src + 4);
        float4 f2 = *(const float4*)(src + 8);
        float4 f3 = *(const float4*)(src + 12);
        short* d = &t[rl][c4];
        d[0]=f2bf(f0.x); d[1]=f2bf(f0.y); d[2]=f2bf(f0.z); d[3]=f2bf(f0.w);
        d[4]=f2bf(f1.x); d[5]=f2bf(f1.y); d[6]=f2bf(f1.z); d[7]=f2bf(f1.w);
        d[8]=f2bf(f2.x); d[9]=f2bf(f2.y); d[10]=f2bf(f2.z); d[11]=f2bf(f2.w);
        d[12]=f2bf(f3.x); d[13]=f2bf(f3.y); d[14]=f2bf(f3.z); d[15]=f2bf(f3.w);
    }
    __syncthreads();
    {
        const int cl = tid >> 2, r4 = (tid & 3) << 4;
        bf16x8 p0, p1;
#pragma unroll
        for (int j = 0; j < 8; ++j) { p0[j] = t[r4 + j][cl]; p1[j] = t[r4 + 8 + j][cl]; }
        short* dst = wt + (size_t)(c0 + cl) * R + r0 + r4;
        *(bf16x8*)dst       = p0;
        *(bf16x8*)(dst + 8) = p1;
    }
}

// ---------------------------------------------------------------------------
// GEMM1: qkv = x @ w_qkv + b_qkv ; scatter to q (scaled 1/8), k, v^T (bf16)
// x fp32 [BT][NC]; wt bf16 [3NC][NC] (pre-transposed). 128x128 tile, BK=32.
// ---------------------------------------------------------------------------
__global__ __launch_bounds__(256)
void qkv_gemm(const float* __restrict__ x, const short* __restrict__ wt,
              const float* __restrict__ bias,
              short* __restrict__ q, short* __restrict__ k, short* __restrict__ vt)
{
    __shared__ short aLds[128][40];
    __shared__ short bLds[128][40];
    const int tid  = threadIdx.x;
    const int lane = tid & 63;
    const int wave = tid >> 6;
    const int waveM = wave & 1;
    const int waveN = wave >> 1;
    const int quad = lane >> 4;
    const int l15  = lane & 15;
    const int m0 = blockIdx.x * 128;
    const int n0 = blockIdx.y * 128;

    f32x4 acc[4][4];
#pragma unroll
    for (int i = 0; i < 4; ++i)
#pragma unroll
        for (int j = 0; j < 4; ++j) acc[i][j] = 0.0f;

    const int arow = tid >> 1;
    const int acb  = (tid & 1) << 4;

    for (int k0 = 0; k0 < NC; k0 += 32) {
        {
            const float* src = x + (size_t)(m0 + arow) * NC + k0 + acb;
            float4 f0 = *(const float4*)(src + 0);
            float4 f1 = *(const float4*)(src + 4);
            float4 f2 = *(const float4*)(src + 8);
            float4 f3 = *(const float4*)(src + 12);
            bf16x8 p0, p1;
            p0[0]=f2bf(f0.x); p0[1]=f2bf(f0.y); p0[2]=f2bf(f0.z); p0[3]=f2bf(f0.w);
            p0[4]=f2bf(f1.x); p0[5]=f2bf(f1.y); p0[6]=f2bf(f1.z); p0[7]=f2bf(f1.w);
            p1[0]=f2bf(f2.x); p1[1]=f2bf(f2.y); p1[2]=f2bf(f2.z); p1[3]=f2bf(f2.w);
            p1[4]=f2bf(f3.x); p1[5]=f2bf(f3.y); p1[6]=f2bf(f3.z); p1[7]=f2bf(f3.w);
            *(bf16x8*)&aLds[arow][acb]     = p0;
            *(bf16x8*)&aLds[arow][acb + 8] = p1;
        }
        {
            const short* src = wt + (size_t)(n0 + arow) * NC + k0 + acb;
            *(bf16x8*)&bLds[arow][acb]     = *(const bf16x8*)src;
            *(bf16x8*)&bLds[arow][acb + 8] = *(const bf16x8*)(src + 8);
        }
        __syncthreads();

        bf16x8 af[4], bfr[4];
#pragma unroll
        for (int mi = 0; mi < 4; ++mi)
            af[mi] = *(const bf16x8*)&aLds[waveM*64 + mi*16 + l15][quad*8];
#pragma unroll
        for (int ni = 0; ni < 4; ++ni)
            bfr[ni] = *(const bf16x8*)&bLds[waveN*64 + ni*16 + l15][quad*8];
#pragma unroll
        for (int mi = 0; mi < 4; ++mi)
#pragma unroll
            for (int ni = 0; ni < 4; ++ni)
                acc[mi][ni] = mfma16(af[mi], bfr[ni], acc[mi][ni]);
        __syncthreads();
    }

#pragma unroll
    for (int mi = 0; mi < 4; ++mi) {
#pragma unroll
        for (int ni = 0; ni < 4; ++ni) {
            const int n = n0 + waveN*64 + ni*16 + l15;
            const float bb = bias[n];
            const int s = n >> 10;
            const int h = (n >> 6) & 15;
            const int d = n & 63;
#pragma unroll
            for (int r = 0; r < 4; ++r) {
                const int m = m0 + waveM*64 + mi*16 + quad*4 + r;
                const int b = m >> 11;
                const int t = m & (NT - 1);
                const float val = acc[mi][ni][r] + bb;
                const size_t bhx = (size_t)(b * NH + h);
                if (s == 0)      q [(bhx * NT + t) * ND + d] = f2bf(val * 0.125f);
                else if (s == 1) k [(bhx * NT + t) * ND + d] = f2bf(val);
                else             vt[(bhx * ND + d) * NT + t] = f2bf(val);
            }
        }
    }
}

// ---------------------------------------------------------------------------
// Flash attention, causal, BARRIER-FREE. Waves fully independent:
// K/V fragments loaded straight from global (L2), P round-trips per-wave LDS.
// Block = 4 waves x 32 q rows; grid.x pairs q-tiles (x, 15-x) for balance.
// 64-key tiles; per-wave causal trim; exp2-domain softmax.
// ---------------------------------------------------------------------------
__global__ __launch_bounds__(256)
void attn(const short* __restrict__ q, const short* __restrict__ k,
          const short* __restrict__ vt, short* __restrict__ ctx)
{
    __shared__ short pLds[4][32][72];
    const int tid  = threadIdx.x;
    const int lane = tid & 63;
    const int wave = tid >> 6;
    const int quad = lane >> 4;
    const int l15  = lane & 15;
    const int bh = blockIdx.y;
    const int b  = bh >> 4;
    const int h  = bh & 15;

    const short* Qp = q  + (size_t)bh * NT * ND;
    const short* Kp = k  + (size_t)bh * NT * ND;
    const short* Vp = vt + (size_t)bh * ND * NT;

    for (int half = 0; half < 2; ++half) {
        const int qtile = (half == 0) ? blockIdx.x : (15 - blockIdx.x);
        const int qb = qtile * 128;
        const int wq0 = qb + wave * 32;
        const int ktend = (wq0 + 32 + 63) >> 6;   // 64-key tiles this wave needs

        bf16x8 qf[2][2];
#pragma unroll
        for (int mi = 0; mi < 2; ++mi)
#pragma unroll
            for (int kd = 0; kd < 2; ++kd)
                qf[mi][kd] = *(const bf16x8*)(Qp + (size_t)(wq0 + mi*16 + l15) * ND + kd*32 + quad*8);

        f32x4 o[2][4];
        float mr[2][4], lr[2][4];
#pragma unroll
        for (int mi = 0; mi < 2; ++mi) {
#pragma unroll
            for (int di = 0; di < 4; ++di) o[mi][di] = 0.0f;
#pragma unroll
            for (int r = 0; r < 4; ++r) { mr[mi][r] = NEG_BIG; lr[mi][r] = 0.0f; }
        }

        // preload K,V frags for tile 0
        bf16x8 kf[4][2], vf[4][2];
#pragma unroll
        for (int ni = 0; ni < 4; ++ni)
#pragma unroll
            for (int kd = 0; kd < 2; ++kd)
                kf[ni][kd] = *(const bf16x8*)(Kp + (size_t)(ni*16 + l15) * ND + kd*32 + quad*8);
#pragma unroll
        for (int di = 0; di < 4; ++di)
#pragma unroll
            for (int kd = 0; kd < 2; ++kd)
                vf[di][kd] = *(const bf16x8*)(Vp + (size_t)(di*16 + l15) * NT + kd*32 + quad*8);

        for (int kt = 0; kt < ktend; ++kt) {
            const int kb = kt << 6;

            // S = Q K^T over 64 keys
            f32x4 s[2][4];
#pragma unroll
            for (int mi = 0; mi < 2; ++mi)
#pragma unroll
                for (int ni = 0; ni < 4; ++ni) {
                    s[mi][ni] = 0.0f;
                    s[mi][ni] = mfma16(qf[mi][0], kf[ni][0], s[mi][ni]);
                    s[mi][ni] = mfma16(qf[mi][1], kf[ni][1], s[mi][ni]);
                }

            // prefetch next tile's K frags (hidden by softmax+PV)
            if (kt + 1 < ktend) {
                const int kb2 = kb + 64;
#pragma unroll
                for (int ni = 0; ni < 4; ++ni)
#pragma unroll
                    for (int kd = 0; kd < 2; ++kd)
                        kf[ni][kd] = *(const bf16x8*)(Kp + (size_t)(kb2 + ni*16 + l15) * ND + kd*32 + quad*8);
            }

            // causal mask (only straddling tiles)
            if (kb + 63 > wq0) {
#pragma unroll
                for (int mi = 0; mi < 2; ++mi)
#pragma unroll
                    for (int ni = 0; ni < 4; ++ni) {
                        const int key = kb + ni*16 + l15;
#pragma unroll
                        for (int r = 0; r < 4; ++r) {
                            const int qrow = wq0 + mi*16 + quad*4 + r;
                            if (key > qrow) s[mi][ni][r] = NEG_BIG;
                        }
                    }
            }

            // online softmax (exp2 domain); key dim spans the 16 lanes of a quad
#pragma unroll
            for (int mi = 0; mi < 2; ++mi) {
                float nm[4], al[4], rs[4], ml[4];
#pragma unroll
                for (int r = 0; r < 4; ++r)
                    nm[r] = fmaxf(fmaxf(s[mi][0][r], s[mi][1][r]), fmaxf(s[mi][2][r], s[mi][3][r]));
#pragma unroll
                for (int off = 1; off < 16; off <<= 1)
#pragma unroll
                    for (int r = 0; r < 4; ++r) nm[r] = fmaxf(nm[r], __shfl_xor(nm[r], off));
#pragma unroll
                for (int r = 0; r < 4; ++r) {
                    const float mnew = fmaxf(mr[mi][r], nm[r]);
                    al[r] = fexp2((mr[mi][r] - mnew) * LOG2E);
                    mr[mi][r] = mnew;
                    ml[r] = mnew * LOG2E;
                    rs[r] = 0.0f;
                }
#pragma unroll
                for (int ni = 0; ni < 4; ++ni)
#pragma unroll
                    for (int r = 0; r < 4; ++r) {
                        const float e = fexp2(fmaf(s[mi][ni][r], LOG2E, -ml[r]));
                        s[mi][ni][r] = e;
                        rs[r] += e;
                    }
#pragma unroll
                for (int off = 1; off < 16; off <<= 1)
#pragma unroll
                    for (int r = 0; r < 4; ++r) rs[r] += __shfl_xor(rs[r], off);
#pragma unroll
                for (int r = 0; r < 4; ++r) lr[mi][r] = lr[mi][r] * al[r] + rs[r];
#pragma unroll
                for (int di = 0; di < 4; ++di)
#pragma unroll
                    for (int r = 0; r < 4; ++r) o[mi][di][r] *= al[r];
#pragma unroll
                for (int ni = 0; ni < 4; ++ni)
#pragma unroll
                    for (int r = 0; r < 4; ++r)
                        pLds[wave][mi*16 + quad*4 + r][ni*16 + l15] = f2bf(s[mi][ni][r]);
            }

            // PV: P(32x64) @ V(64x64); per-wave LDS, in-wave ordering, no barrier
            bf16x8 pf[2][2];
#pragma unroll
            for (int mi = 0; mi < 2; ++mi)
#pragma unroll
                for (int kd = 0; kd < 2; ++kd)
                    pf[mi][kd] = *(const bf16x8*)&pLds[wave][mi*16 + l15][kd*32 + quad*8];
#pragma unroll
            for (int mi = 0; mi < 2; ++mi)
#pragma unroll
                for (int di = 0; di < 4; ++di) {
                    o[mi][di] = mfma16(pf[mi][0], vf[di][0], o[mi][di]);
                    o[mi][di] = mfma16(pf[mi][1], vf[di][1], o[mi][di]);
                }

            // prefetch next tile's V frags (hidden by next S + softmax)
            if (kt + 1 < ktend) {
                const int kb2 = kb + 64;
#pragma unroll
                for (int di = 0; di < 4; ++di)
#pragma unroll
                    for (int kd = 0; kd < 2; ++kd)
                        vf[di][kd] = *(const bf16x8*)(Vp + (size_t)(di*16 + l15) * NT + kb2 + kd*32 + quad*8);
            }
        }

        // epilogue
#pragma unroll
        for (int mi = 0; mi < 2; ++mi)
#pragma unroll
            for (int di = 0; di < 4; ++di)
#pragma unroll
                for (int r = 0; r < 4; ++r) {
                    const int t = wq0 + mi*16 + quad*4 + r;
                    const float val = o[mi][di][r] / lr[mi][r];
                    ctx[((size_t)(b * NT + t)) * NC + h*64 + di*16 + l15] = f2bf(val);
                }
    }
}

// ---------------------------------------------------------------------------
// GEMM2: out = ctx @ w_out + b_out (fp32 out). ctx bf16, wt bf16 [NC][NC] pre-T
// ---------------------------------------------------------------------------
__global__ __launch_bounds__(256)
void out_gemm(const short* __restrict__ a, const short* __restrict__ wt,
              const float* __restrict__ bias, float* __restrict__ out)
{
    __shared__ short aLds[128][40];
    __shared__ short bLds[128][40];
    const int tid  = threadIdx.x;
    const int lane = tid & 63;
    const int wave = tid >> 6;
    const int waveM = wave & 1;
    const int waveN = wave >> 1;
    const int quad = lane >> 4;
    const int l15  = lane & 15;
    const int m0 = blockIdx.x * 128;
    const int n0 = blockIdx.y * 128;

    f32x4 acc[4][4];
#pragma unroll
    for (int i = 0; i < 4; ++i)
#pragma unroll
        for (int j = 0; j < 4; ++j) acc[i][j] = 0.0f;

    const int arow = tid >> 1;
    const int acb  = (tid & 1) << 4;

    for (int k0 = 0; k0 < NC; k0 += 32) {
        {
            const short* src = a + (size_t)(m0 + arow) * NC + k0 + acb;
            *(bf16x8*)&aLds[arow][acb]     = *(const bf16x8*)src;
            *(bf16x8*)&aLds[arow][acb + 8] = *(const bf16x8*)(src + 8);
        }
        {
            const short* src = wt + (size_t)(n0 + arow) * NC + k0 + acb;
            *(bf16x8*)&bLds[arow][acb]     = *(const bf16x8*)src;
            *(bf16x8*)&bLds[arow][acb + 8] = *(const bf16x8*)(src + 8);
        }
        __syncthreads();

        bf16x8 af[4], bfr[4];
#pragma unroll
        for (int mi = 0; mi < 4; ++mi)
            af[mi] = *(const bf16x8*)&aLds[waveM*64 + mi*16 + l15][quad*8];
#pragma unroll
        for (int ni = 0; ni < 4; ++ni)
            bfr[ni] = *(const bf16x8*)&bLds[waveN*64 + ni*16 + l15][quad*8];
#pragma unroll
        for (int mi = 0; mi < 4; ++mi)
#pragma unroll
            for (int ni = 0; ni < 4; ++ni)
                acc[mi][ni] = mfma16(af[mi], bfr[ni], acc[mi][ni]);
        __syncthreads();
    }

#pragma unroll
    for (int mi = 0; mi < 4; ++mi) {
#pragma unroll
        for (int ni = 0; ni < 4; ++ni) {
            const int n = n0 + waveN*64 + ni*16 + l15;
            const float bb = bias[n];
#pragma unroll
            for (int r = 0; r < 4; ++r) {
                const int m = m0 + waveM*64 + mi*16 + quad*4 + r;
                out[(size_t)m * NC + n] = acc[mi][ni][r] + bb;
            }
        }
    }
}

extern "C" void kernel_launch(void* const* d_in, const int* in_sizes, int n_in,
                              void* d_out, int out_size, void* d_ws, size_t ws_size,
                              hipStream_t stream)
{
    const float* x     = (const float*)d_in[0];
    const float* w_qkv = (const float*)d_in[1];
    const float* b_qkv = (const float*)d_in[2];
    const float* w_out = (const float*)d_in[3];
    const float* b_out = (const float*)d_in[4];
    float* out = (float*)d_out;

    const size_t SZ = (size_t)NB * NH * NT * ND;   // 8.39M elems, 16.8 MB bf16
    short* q   = (short*)d_ws;
    short* kk  = q  + SZ;
    short* vt  = kk + SZ;
    short* ctx = vt + SZ;
    // weight transposes alias dead regions (stream-serial ordering makes this safe):
    short* wTq = ctx;   // used only by qkv_gemm, before attn writes ctx (6.3MB < 16.8MB)
    short* wTo = q;     // written after attn (q dead), used by out_gemm (2MB < 16.8MB)

    hipLaunchKernelGGL(transpose_w, dim3(16, 48), dim3(256), 0, stream,
                       w_qkv, wTq, NC, 3*NC);
    hipLaunchKernelGGL(qkv_gemm, dim3(BT/128, (3*NC)/128), dim3(256), 0, stream,
                       x, wTq, b_qkv, q, kk, vt);
    hipLaunchKernelGGL(attn, dim3(8, NB*NH), dim3(256), 0, stream,
                       q, kk, vt, ctx);
    hipLaunchKernelGGL(transpose_w, dim3(16, 16), dim3(256), 0, stream,
                       w_out, wTo, NC, NC);
    hipLaunchKernelGGL(out_gemm, dim3(BT/128, NC/128), dim3(256), 0, stream,
                       ctx, wTo, b_out, out);
}

// Round 3
// 357.004 us; speedup vs baseline: 1.5763x; 1.1238x over previous
//
#include <hip/hip_runtime.h>
#include <hip/hip_bf16.h>

#define NB 4
#define NT 2048
#define NC 1024
#define NH 16
#define ND 64
#define BT (NB*NT)
#define LOG2E 1.4426950408889634f
#define NEG_BIG (-3.0e38f)

typedef __attribute__((ext_vector_type(8))) short bf16x8;
typedef __attribute__((ext_vector_type(4))) float f32x4;

static __device__ __forceinline__ short f2bf(float f) {
    union { float f; unsigned u; } v; v.f = f;
    unsigned r = (v.u + 0x7fffu + ((v.u >> 16) & 1u)) >> 16;
    return (short)r;
}

static __device__ __forceinline__ f32x4 mfma16(bf16x8 a, bf16x8 b, f32x4 c) {
    return __builtin_amdgcn_mfma_f32_16x16x32_bf16(a, b, c, 0, 0, 0);
}

static __device__ __forceinline__ float fexp2(float x) {
#if __has_builtin(__builtin_amdgcn_exp2f)
    return __builtin_amdgcn_exp2f(x);
#else
    return exp2f(x);
#endif
}

// ---------------------------------------------------------------------------
// x (fp32) -> bf16, flat. 8 elems/thread.
// ---------------------------------------------------------------------------
__global__ __launch_bounds__(256)
void xcvt(const float* __restrict__ x, short* __restrict__ xb)
{
    const size_t i = ((size_t)blockIdx.x * 256 + threadIdx.x) * 8;
    float4 f0 = *(const float4*)(x + i);
    float4 f1 = *(const float4*)(x + i + 4);
    bf16x8 p;
    p[0]=f2bf(f0.x); p[1]=f2bf(f0.y); p[2]=f2bf(f0.z); p[3]=f2bf(f0.w);
    p[4]=f2bf(f1.x); p[5]=f2bf(f1.y); p[6]=f2bf(f1.z); p[7]=f2bf(f1.w);
    *(bf16x8*)(xb + i) = p;
}

// ---------------------------------------------------------------------------
// Transpose + convert: w fp32 [R][Cn] -> wt bf16 [Cn][R]. 64x64 tiles.
// ---------------------------------------------------------------------------
__global__ __launch_bounds__(256)
void transpose_w(const float* __restrict__ w, short* __restrict__ wt, int R, int Cn)
{
    __shared__ short t[64][72];
    const int tid = threadIdx.x;
    const int r0 = blockIdx.x * 64;
    const int c0 = blockIdx.y * 64;
    {
        const int rl = tid >> 2, c4 = (tid & 3) << 4;
        const float* src = w + (size_t)(r0 + rl) * Cn + c0 + c4;
        float4 f0 = *(const float4*)(src + 0);
        float4 f1 = *(const float4*)(src + 4);
        float4 f2 = *(const float4*)(src + 8);
        float4 f3 = *(const float4*)(src + 12);
        short* d = &t[rl][c4];
        d[0]=f2bf(f0.x); d[1]=f2bf(f0.y); d[2]=f2bf(f0.z); d[3]=f2bf(f0.w);
        d[4]=f2bf(f1.x); d[5]=f2bf(f1.y); d[6]=f2bf(f1.z); d[7]=f2bf(f1.w);
        d[8]=f2bf(f2.x); d[9]=f2bf(f2.y); d[10]=f2bf(f2.z); d[11]=f2bf(f2.w);
        d[12]=f2bf(f3.x); d[13]=f2bf(f3.y); d[14]=f2bf(f3.z); d[15]=f2bf(f3.w);
    }
    __syncthreads();
    {
        const int cl = tid >> 2, r4 = (tid & 3) << 4;
        bf16x8 p0, p1;
#pragma unroll
        for (int j = 0; j < 8; ++j) { p0[j] = t[r4 + j][cl]; p1[j] = t[r4 + 8 + j][cl]; }
        short* dst = wt + (size_t)(c0 + cl) * R + r0 + r4;
        *(bf16x8*)dst       = p0;
        *(bf16x8*)(dst + 8) = p1;
    }
}

// ---------------------------------------------------------------------------
// GEMM1: qkv = xb @ wt^T + b_qkv ; scatter to q (scaled 1/8), k, v^T (bf16)
// xb bf16 [BT][NC]; wt bf16 [3NC][NC] (pre-transposed). 128x128 tile, BK=32.
// ---------------------------------------------------------------------------
__global__ __launch_bounds__(256)
void qkv_gemm(const short* __restrict__ xb, const short* __restrict__ wt,
              const float* __restrict__ bias,
              short* __restrict__ q, short* __restrict__ k, short* __restrict__ vt)
{
    __shared__ short aLds[128][40];
    __shared__ short bLds[128][40];
    const int tid  = threadIdx.x;
    const int lane = tid & 63;
    const int wave = tid >> 6;
    const int waveM = wave & 1;
    const int waveN = wave >> 1;
    const int quad = lane >> 4;
    const int l15  = lane & 15;
    const int m0 = blockIdx.x * 128;
    const int n0 = blockIdx.y * 128;

    f32x4 acc[4][4];
#pragma unroll
    for (int i = 0; i < 4; ++i)
#pragma unroll
        for (int j = 0; j < 4; ++j) acc[i][j] = 0.0f;

    const int arow = tid >> 1;
    const int acb  = (tid & 1) << 4;

    for (int k0 = 0; k0 < NC; k0 += 32) {
        {
            const short* src = xb + (size_t)(m0 + arow) * NC + k0 + acb;
            *(bf16x8*)&aLds[arow][acb]     = *(const bf16x8*)src;
            *(bf16x8*)&aLds[arow][acb + 8] = *(const bf16x8*)(src + 8);
        }
        {
            const short* src = wt + (size_t)(n0 + arow) * NC + k0 + acb;
            *(bf16x8*)&bLds[arow][acb]     = *(const bf16x8*)src;
            *(bf16x8*)&bLds[arow][acb + 8] = *(const bf16x8*)(src + 8);
        }
        __syncthreads();

        bf16x8 af[4], bfr[4];
#pragma unroll
        for (int mi = 0; mi < 4; ++mi)
            af[mi] = *(const bf16x8*)&aLds[waveM*64 + mi*16 + l15][quad*8];
#pragma unroll
        for (int ni = 0; ni < 4; ++ni)
            bfr[ni] = *(const bf16x8*)&bLds[waveN*64 + ni*16 + l15][quad*8];
#pragma unroll
        for (int mi = 0; mi < 4; ++mi)
#pragma unroll
            for (int ni = 0; ni < 4; ++ni)
                acc[mi][ni] = mfma16(af[mi], bfr[ni], acc[mi][ni]);
        __syncthreads();
    }

#pragma unroll
    for (int mi = 0; mi < 4; ++mi) {
#pragma unroll
        for (int ni = 0; ni < 4; ++ni) {
            const int n = n0 + waveN*64 + ni*16 + l15;
            const float bb = bias[n];
            const int s = n >> 10;
            const int h = (n >> 6) & 15;
            const int d = n & 63;
#pragma unroll
            for (int r = 0; r < 4; ++r) {
                const int m = m0 + waveM*64 + mi*16 + quad*4 + r;
                const int b = m >> 11;
                const int t = m & (NT - 1);
                const float val = acc[mi][ni][r] + bb;
                const size_t bhx = (size_t)(b * NH + h);
                if (s == 0)      q [(bhx * NT + t) * ND + d] = f2bf(val * 0.125f);
                else if (s == 1) k [(bhx * NT + t) * ND + d] = f2bf(val);
                else             vt[(bhx * ND + d) * NT + t] = f2bf(val);
            }
        }
    }
}

// ---------------------------------------------------------------------------
// Flash attention, causal. ONE WAVE PER BLOCK (64 thr) — fully independent
// work-pool: grid (bh=64, tile=64), longest tiles dispatched first.
// K/V frags straight from global (L2); P round-trip via private LDS.
// ---------------------------------------------------------------------------
__global__ __launch_bounds__(64)
void attn(const short* __restrict__ q, const short* __restrict__ k,
          const short* __restrict__ vt, short* __restrict__ ctx)
{
    __shared__ short pLds[32][72];
    const int lane = threadIdx.x;
    const int quad = lane >> 4;
    const int l15  = lane & 15;
    const int bh = blockIdx.x;
    const int b  = bh >> 4;
    const int h  = bh & 15;
    const int qtile = 63 - (int)blockIdx.y;   // longest-first dispatch
    const int wq0 = qtile * 32;
    const int ktend = (wq0 + 32 + 63) >> 6;

    const short* Qp = q  + (size_t)bh * NT * ND;
    const short* Kp = k  + (size_t)bh * NT * ND;
    const short* Vp = vt + (size_t)bh * ND * NT;

    bf16x8 qf[2][2];
#pragma unroll
    for (int mi = 0; mi < 2; ++mi)
#pragma unroll
        for (int kd = 0; kd < 2; ++kd)
            qf[mi][kd] = *(const bf16x8*)(Qp + (size_t)(wq0 + mi*16 + l15) * ND + kd*32 + quad*8);

    f32x4 o[2][4];
    float mr[2][4], lr[2][4];
#pragma unroll
    for (int mi = 0; mi < 2; ++mi) {
#pragma unroll
        for (int di = 0; di < 4; ++di) o[mi][di] = 0.0f;
#pragma unroll
        for (int r = 0; r < 4; ++r) { mr[mi][r] = NEG_BIG; lr[mi][r] = 0.0f; }
    }

    // preload K,V frags for tile 0
    bf16x8 kf[4][2], vf[4][2];
#pragma unroll
    for (int ni = 0; ni < 4; ++ni)
#pragma unroll
        for (int kd = 0; kd < 2; ++kd)
            kf[ni][kd] = *(const bf16x8*)(Kp + (size_t)(ni*16 + l15) * ND + kd*32 + quad*8);
#pragma unroll
    for (int di = 0; di < 4; ++di)
#pragma unroll
        for (int kd = 0; kd < 2; ++kd)
            vf[di][kd] = *(const bf16x8*)(Vp + (size_t)(di*16 + l15) * NT + kd*32 + quad*8);

    for (int kt = 0; kt < ktend; ++kt) {
        const int kb = kt << 6;

        // S = Q K^T over 64 keys
        f32x4 s[2][4];
#pragma unroll
        for (int mi = 0; mi < 2; ++mi)
#pragma unroll
            for (int ni = 0; ni < 4; ++ni) {
                s[mi][ni] = 0.0f;
                s[mi][ni] = mfma16(qf[mi][0], kf[ni][0], s[mi][ni]);
                s[mi][ni] = mfma16(qf[mi][1], kf[ni][1], s[mi][ni]);
            }

        // prefetch next tile's K frags (hidden by softmax+PV)
        if (kt + 1 < ktend) {
            const int kb2 = kb + 64;
#pragma unroll
            for (int ni = 0; ni < 4; ++ni)
#pragma unroll
                for (int kd = 0; kd < 2; ++kd)
                    kf[ni][kd] = *(const bf16x8*)(Kp + (size_t)(kb2 + ni*16 + l15) * ND + kd*32 + quad*8);
        }

        // causal mask (only straddling tiles)
        if (kb + 63 > wq0) {
#pragma unroll
            for (int mi = 0; mi < 2; ++mi)
#pragma unroll
                for (int ni = 0; ni < 4; ++ni) {
                    const int key = kb + ni*16 + l15;
#pragma unroll
                    for (int r = 0; r < 4; ++r) {
                        const int qrow = wq0 + mi*16 + quad*4 + r;
                        if (key > qrow) s[mi][ni][r] = NEG_BIG;
                    }
                }
        }

        // online softmax (exp2 domain); key dim spans the 16 lanes of a quad
#pragma unroll
        for (int mi = 0; mi < 2; ++mi) {
            float nm[4], al[4], rs[4], ml[4];
#pragma unroll
            for (int r = 0; r < 4; ++r)
                nm[r] = fmaxf(fmaxf(s[mi][0][r], s[mi][1][r]), fmaxf(s[mi][2][r], s[mi][3][r]));
#pragma unroll
            for (int off = 1; off < 16; off <<= 1)
#pragma unroll
                for (int r = 0; r < 4; ++r) nm[r] = fmaxf(nm[r], __shfl_xor(nm[r], off));
#pragma unroll
            for (int r = 0; r < 4; ++r) {
                const float mnew = fmaxf(mr[mi][r], nm[r]);
                al[r] = fexp2((mr[mi][r] - mnew) * LOG2E);
                mr[mi][r] = mnew;
                ml[r] = mnew * LOG2E;
                rs[r] = 0.0f;
            }
#pragma unroll
            for (int ni = 0; ni < 4; ++ni)
#pragma unroll
                for (int r = 0; r < 4; ++r) {
                    const float e = fexp2(fmaf(s[mi][ni][r], LOG2E, -ml[r]));
                    s[mi][ni][r] = e;
                    rs[r] += e;
                }
#pragma unroll
            for (int off = 1; off < 16; off <<= 1)
#pragma unroll
                for (int r = 0; r < 4; ++r) rs[r] += __shfl_xor(rs[r], off);
#pragma unroll
            for (int r = 0; r < 4; ++r) lr[mi][r] = lr[mi][r] * al[r] + rs[r];
#pragma unroll
            for (int di = 0; di < 4; ++di)
#pragma unroll
                for (int r = 0; r < 4; ++r) o[mi][di][r] *= al[r];
#pragma unroll
            for (int ni = 0; ni < 4; ++ni)
#pragma unroll
                for (int r = 0; r < 4; ++r)
                    pLds[mi*16 + quad*4 + r][ni*16 + l15] = f2bf(s[mi][ni][r]);
        }

        // PV: P(32x64) @ V(64x64); single wave, in-order LDS, no barrier
        bf16x8 pf[2][2];
#pragma unroll
        for (int mi = 0; mi < 2; ++mi)
#pragma unroll
            for (int kd = 0; kd < 2; ++kd)
                pf[mi][kd] = *(const bf16x8*)&pLds[mi*16 + l15][kd*32 + quad*8];
#pragma unroll
        for (int mi = 0; mi < 2; ++mi)
#pragma unroll
            for (int di = 0; di < 4; ++di) {
                o[mi][di] = mfma16(pf[mi][0], vf[di][0], o[mi][di]);
                o[mi][di] = mfma16(pf[mi][1], vf[di][1], o[mi][di]);
            }

        // prefetch next tile's V frags (hidden by next S + softmax)
        if (kt + 1 < ktend) {
            const int kb2 = kb + 64;
#pragma unroll
            for (int di = 0; di < 4; ++di)
#pragma unroll
                for (int kd = 0; kd < 2; ++kd)
                    vf[di][kd] = *(const bf16x8*)(Vp + (size_t)(di*16 + l15) * NT + kb2 + kd*32 + quad*8);
        }
    }

    // epilogue
#pragma unroll
    for (int mi = 0; mi < 2; ++mi)
#pragma unroll
        for (int di = 0; di < 4; ++di)
#pragma unroll
            for (int r = 0; r < 4; ++r) {
                const int t = wq0 + mi*16 + quad*4 + r;
                const float val = o[mi][di][r] / lr[mi][r];
                ctx[((size_t)(b * NT + t)) * NC + h*64 + di*16 + l15] = f2bf(val);
            }
}

// ---------------------------------------------------------------------------
// GEMM2: out = ctx @ w_out + b_out (fp32 out). ctx bf16, wt bf16 [NC][NC] pre-T
// ---------------------------------------------------------------------------
__global__ __launch_bounds__(256)
void out_gemm(const short* __restrict__ a, const short* __restrict__ wt,
              const float* __restrict__ bias, float* __restrict__ out)
{
    __shared__ short aLds[128][40];
    __shared__ short bLds[128][40];
    const int tid  = threadIdx.x;
    const int lane = tid & 63;
    const int wave = tid >> 6;
    const int waveM = wave & 1;
    const int waveN = wave >> 1;
    const int quad = lane >> 4;
    const int l15  = lane & 15;
    const int m0 = blockIdx.x * 128;
    const int n0 = blockIdx.y * 128;

    f32x4 acc[4][4];
#pragma unroll
    for (int i = 0; i < 4; ++i)
#pragma unroll
        for (int j = 0; j < 4; ++j) acc[i][j] = 0.0f;

    const int arow = tid >> 1;
    const int acb  = (tid & 1) << 4;

    for (int k0 = 0; k0 < NC; k0 += 32) {
        {
            const short* src = a + (size_t)(m0 + arow) * NC + k0 + acb;
            *(bf16x8*)&aLds[arow][acb]     = *(const bf16x8*)src;
            *(bf16x8*)&aLds[arow][acb + 8] = *(const bf16x8*)(src + 8);
        }
        {
            const short* src = wt + (size_t)(n0 + arow) * NC + k0 + acb;
            *(bf16x8*)&bLds[arow][acb]     = *(const bf16x8*)src;
            *(bf16x8*)&bLds[arow][acb + 8] = *(const bf16x8*)(src + 8);
        }
        __syncthreads();

        bf16x8 af[4], bfr[4];
#pragma unroll
        for (int mi = 0; mi < 4; ++mi)
            af[mi] = *(const bf16x8*)&aLds[waveM*64 + mi*16 + l15][quad*8];
#pragma unroll
        for (int ni = 0; ni < 4; ++ni)
            bfr[ni] = *(const bf16x8*)&bLds[waveN*64 + ni*16 + l15][quad*8];
#pragma unroll
        for (int mi = 0; mi < 4; ++mi)
#pragma unroll
            for (int ni = 0; ni < 4; ++ni)
                acc[mi][ni] = mfma16(af[mi], bfr[ni], acc[mi][ni]);
        __syncthreads();
    }

#pragma unroll
    for (int mi = 0; mi < 4; ++mi) {
#pragma unroll
        for (int ni = 0; ni < 4; ++ni) {
            const int n = n0 + waveN*64 + ni*16 + l15;
            const float bb = bias[n];
#pragma unroll
            for (int r = 0; r < 4; ++r) {
                const int m = m0 + waveM*64 + mi*16 + quad*4 + r;
                out[(size_t)m * NC + n] = acc[mi][ni][r] + bb;
            }
        }
    }
}

extern "C" void kernel_launch(void* const* d_in, const int* in_sizes, int n_in,
                              void* d_out, int out_size, void* d_ws, size_t ws_size,
                              hipStream_t stream)
{
    const float* x     = (const float*)d_in[0];
    const float* w_qkv = (const float*)d_in[1];
    const float* b_qkv = (const float*)d_in[2];
    const float* w_out = (const float*)d_in[3];
    const float* b_out = (const float*)d_in[4];
    float* out = (float*)d_out;

    const size_t SZ = (size_t)NB * NH * NT * ND;   // 8.39M elems, 16.8 MB bf16
    short* q   = (short*)d_ws;
    short* kk  = q  + SZ;
    short* vt  = kk + SZ;
    short* ctx = vt + SZ;
    short* xbf = ctx + SZ;   // 5*SZ*2 = 83.9 MB total
    // aliases into dead regions (stream-serial ordering makes this safe):
    short* wTq = ctx;   // live only until attn overwrites ctx (6.3MB < 16.8MB)
    short* wTo = xbf;   // xbf dead after qkv_gemm; wTo used by out_gemm (2MB)

    hipLaunchKernelGGL(xcvt, dim3(BT*NC/(256*8)), dim3(256), 0, stream, x, xbf);
    hipLaunchKernelGGL(transpose_w, dim3(16, 48), dim3(256), 0, stream,
                       w_qkv, wTq, NC, 3*NC);
    hipLaunchKernelGGL(qkv_gemm, dim3(BT/128, (3*NC)/128), dim3(256), 0, stream,
                       xbf, wTq, b_qkv, q, kk, vt);
    hipLaunchKernelGGL(attn, dim3(NB*NH, NT/32), dim3(64), 0, stream,
                       q, kk, vt, ctx);
    hipLaunchKernelGGL(transpose_w, dim3(16, 16), dim3(256), 0, stream,
                       w_out, wTo, NC, NC);
    hipLaunchKernelGGL(out_gemm, dim3(BT/128, NC/128), dim3(256), 0, stream,
                       ctx, wTo, b_out, out);
}

// Round 5
// 326.917 us; speedup vs baseline: 1.7214x; 1.0920x over previous
//
#include <hip/hip_runtime.h>
#include <hip/hip_bf16.h>

#define NB 4
#define NT 2048
#define NC 1024
#define NH 16
#define ND 64
#define BT (NB*NT)
#define LOG2E 1.4426950408889634f
#define NEG_BIG (-3.0e38f)

typedef __attribute__((ext_vector_type(8))) short bf16x8;
typedef __attribute__((ext_vector_type(4))) float f32x4;

static __device__ __forceinline__ short f2bf(float f) {
    union { float f; unsigned u; } v; v.f = f;
    unsigned r = (v.u + 0x7fffu + ((v.u >> 16) & 1u)) >> 16;
    return (short)r;
}

static __device__ __forceinline__ unsigned pk2(float a, float b) {
    return (unsigned)(unsigned short)f2bf(a) | ((unsigned)(unsigned short)f2bf(b) << 16);
}

static __device__ __forceinline__ f32x4 vmax4(f32x4 a, f32x4 b) {
    f32x4 r;
    r[0] = fmaxf(a[0], b[0]); r[1] = fmaxf(a[1], b[1]);
    r[2] = fmaxf(a[2], b[2]); r[3] = fmaxf(a[3], b[3]);
    return r;
}

static __device__ __forceinline__ f32x4 mfma16(bf16x8 a, bf16x8 b, f32x4 c) {
    return __builtin_amdgcn_mfma_f32_16x16x32_bf16(a, b, c, 0, 0, 0);
}

static __device__ __forceinline__ float fexp2(float x) {
#if __has_builtin(__builtin_amdgcn_exp2f)
    return __builtin_amdgcn_exp2f(x);
#else
    return exp2f(x);
#endif
}

// ---------------------------------------------------------------------------
// x (fp32) -> bf16, flat. 8 elems/thread.
// ---------------------------------------------------------------------------
__global__ __launch_bounds__(256)
void xcvt(const float* __restrict__ x, short* __restrict__ xb)
{
    const size_t i = ((size_t)blockIdx.x * 256 + threadIdx.x) * 8;
    float4 f0 = *(const float4*)(x + i);
    float4 f1 = *(const float4*)(x + i + 4);
    bf16x8 p;
    p[0]=f2bf(f0.x); p[1]=f2bf(f0.y); p[2]=f2bf(f0.z); p[3]=f2bf(f0.w);
    p[4]=f2bf(f1.x); p[5]=f2bf(f1.y); p[6]=f2bf(f1.z); p[7]=f2bf(f1.w);
    *(bf16x8*)(xb + i) = p;
}

// ---------------------------------------------------------------------------
// Transpose + convert: w fp32 [R][Cn] -> wt bf16 [Cn][R]. 64x64 tiles.
// ---------------------------------------------------------------------------
__global__ __launch_bounds__(256)
void transpose_w(const float* __restrict__ w, short* __restrict__ wt, int R, int Cn)
{
    __shared__ short t[64][72];
    const int tid = threadIdx.x;
    const int r0 = blockIdx.x * 64;
    const int c0 = blockIdx.y * 64;
    {
        const int rl = tid >> 2, c4 = (tid & 3) << 4;
        const float* src = w + (size_t)(r0 + rl) * Cn + c0 + c4;
        float4 f0 = *(const float4*)(src + 0);
        float4 f1 = *(const float4*)(src + 4);
        float4 f2 = *(const float4*)(src + 8);
        float4 f3 = *(const float4*)(src + 12);
        short* d = &t[rl][c4];
        d[0]=f2bf(f0.x); d[1]=f2bf(f0.y); d[2]=f2bf(f0.z); d[3]=f2bf(f0.w);
        d[4]=f2bf(f1.x); d[5]=f2bf(f1.y); d[6]=f2bf(f1.z); d[7]=f2bf(f1.w);
        d[8]=f2bf(f2.x); d[9]=f2bf(f2.y); d[10]=f2bf(f2.z); d[11]=f2bf(f2.w);
        d[12]=f2bf(f3.x); d[13]=f2bf(f3.y); d[14]=f2bf(f3.z); d[15]=f2bf(f3.w);
    }
    __syncthreads();
    {
        const int cl = tid >> 2, r4 = (tid & 3) << 4;
        bf16x8 p0, p1;
#pragma unroll
        for (int j = 0; j < 8; ++j) { p0[j] = t[r4 + j][cl]; p1[j] = t[r4 + 8 + j][cl]; }
        short* dst = wt + (size_t)(c0 + cl) * R + r0 + r4;
        *(bf16x8*)dst       = p0;
        *(bf16x8*)(dst + 8) = p1;
    }
}

// ---------------------------------------------------------------------------
// GEMM1: qkv = xb @ wt^T + b_qkv ; scatter to q (scaled 1/8), k, v^T (bf16)
// xb bf16 [BT][NC]; wt bf16 [3NC][NC] (pre-transposed). 128x128 tile, BK=64.
// ---------------------------------------------------------------------------
__global__ __launch_bounds__(256)
void qkv_gemm(const short* __restrict__ xb, const short* __restrict__ wt,
              const float* __restrict__ bias,
              short* __restrict__ q, short* __restrict__ k, short* __restrict__ vt)
{
    __shared__ short aLds[128][72];
    __shared__ short bLds[128][72];
    const int tid  = threadIdx.x;
    const int lane = tid & 63;
    const int wave = tid >> 6;
    const int waveM = wave & 1;
    const int waveN = wave >> 1;
    const int quad = lane >> 4;
    const int l15  = lane & 15;
    const int m0 = blockIdx.x * 128;
    const int n0 = blockIdx.y * 128;

    f32x4 acc[4][4];
#pragma unroll
    for (int i = 0; i < 4; ++i)
#pragma unroll
        for (int j = 0; j < 4; ++j) acc[i][j] = 0.0f;

    const int srow = tid >> 1;
    const int scol = (tid & 1) * 32;

    for (int k0 = 0; k0 < NC; k0 += 64) {
        {
            const short* sa = xb + (size_t)(m0 + srow) * NC + k0 + scol;
            *(bf16x8*)&aLds[srow][scol]      = *(const bf16x8*)sa;
            *(bf16x8*)&aLds[srow][scol + 8]  = *(const bf16x8*)(sa + 8);
            *(bf16x8*)&aLds[srow][scol + 16] = *(const bf16x8*)(sa + 16);
            *(bf16x8*)&aLds[srow][scol + 24] = *(const bf16x8*)(sa + 24);
        }
        {
            const short* sb = wt + (size_t)(n0 + srow) * NC + k0 + scol;
            *(bf16x8*)&bLds[srow][scol]      = *(const bf16x8*)sb;
            *(bf16x8*)&bLds[srow][scol + 8]  = *(const bf16x8*)(sb + 8);
            *(bf16x8*)&bLds[srow][scol + 16] = *(const bf16x8*)(sb + 16);
            *(bf16x8*)&bLds[srow][scol + 24] = *(const bf16x8*)(sb + 24);
        }
        __syncthreads();

#pragma unroll
        for (int kd = 0; kd < 2; ++kd) {
            bf16x8 af[4], bfr[4];
#pragma unroll
            for (int mi = 0; mi < 4; ++mi)
                af[mi] = *(const bf16x8*)&aLds[waveM*64 + mi*16 + l15][kd*32 + quad*8];
#pragma unroll
            for (int ni = 0; ni < 4; ++ni)
                bfr[ni] = *(const bf16x8*)&bLds[waveN*64 + ni*16 + l15][kd*32 + quad*8];
#pragma unroll
            for (int mi = 0; mi < 4; ++mi)
#pragma unroll
                for (int ni = 0; ni < 4; ++ni)
                    acc[mi][ni] = mfma16(af[mi], bfr[ni], acc[mi][ni]);
        }
        __syncthreads();
    }

#pragma unroll
    for (int mi = 0; mi < 4; ++mi) {
#pragma unroll
        for (int ni = 0; ni < 4; ++ni) {
            const int n = n0 + waveN*64 + ni*16 + l15;
            const float bb = bias[n];
            const int s = n >> 10;
            const int h = (n >> 6) & 15;
            const int d = n & 63;
#pragma unroll
            for (int r = 0; r < 4; ++r) {
                const int m = m0 + waveM*64 + mi*16 + quad*4 + r;
                const int b = m >> 11;
                const int t = m & (NT - 1);
                const float val = acc[mi][ni][r] + bb;
                const size_t bhx = (size_t)(b * NH + h);
                if (s == 0)      q [(bhx * NT + t) * ND + d] = f2bf(val * 0.125f);
                else if (s == 1) k [(bhx * NT + t) * ND + d] = f2bf(val);
                else             vt[(bhx * ND + d) * NT + t] = f2bf(val);
            }
        }
    }
}

// ---------------------------------------------------------------------------
// Flash attention, causal, TRANSPOSED dataflow: S^T = K Q^T, O^T = V^T P^T.
// C-layout puts q-row on the lane axis -> in-lane softmax reduction, scalar
// m/l per lane, b64 P writes / b128 P reads, packed b64 ctx stores.
// One wave per block; wave handles uniform pair (qtile y, 63-y). No barriers.
// ---------------------------------------------------------------------------
__global__ __launch_bounds__(64)
void attn(const short* __restrict__ q, const short* __restrict__ k,
          const short* __restrict__ vt, short* __restrict__ ctx)
{
    __shared__ short pLds[32][72];
    const int lane = threadIdx.x;
    const int quad = lane >> 4;
    const int l15  = lane & 15;
    const int bh = blockIdx.x;
    const int b  = bh >> 4;
    const int h  = bh & 15;

    const short* Qp = q  + (size_t)bh * NT * ND;
    const short* Kp = k  + (size_t)bh * NT * ND;
    const short* Vp = vt + (size_t)bh * ND * NT;

    for (int half = 0; half < 2; ++half) {
        const int qtile = half ? (63 - (int)blockIdx.y) : (int)blockIdx.y;
        const int wq0 = qtile * 32;
        const int ktend = (wq0 + 95) >> 6;

        // Q as B-operand frags: lane = q-row, regs = d
        bf16x8 qf[2][2];
#pragma unroll
        for (int mi = 0; mi < 2; ++mi)
#pragma unroll
            for (int kd = 0; kd < 2; ++kd)
                qf[mi][kd] = *(const bf16x8*)(Qp + (size_t)(wq0 + mi*16 + l15) * ND + kd*32 + quad*8);

        f32x4 ot[4][2];             // [di][mi], O^T: row=d, col=q-row
        float m_r[2], l_r[2];
#pragma unroll
        for (int di = 0; di < 4; ++di)
#pragma unroll
            for (int mi = 0; mi < 2; ++mi) ot[di][mi] = 0.0f;
        m_r[0] = m_r[1] = NEG_BIG;
        l_r[0] = l_r[1] = 0.0f;

        // preload tile-0 K (A-op) and V^T (A-op) frags
        bf16x8 kf[4][2], vf[4][2];
#pragma unroll
        for (int ni = 0; ni < 4; ++ni)
#pragma unroll
            for (int kd = 0; kd < 2; ++kd)
                kf[ni][kd] = *(const bf16x8*)(Kp + (size_t)(ni*16 + l15) * ND + kd*32 + quad*8);
#pragma unroll
        for (int di = 0; di < 4; ++di)
#pragma unroll
            for (int kd = 0; kd < 2; ++kd)
                vf[di][kd] = *(const bf16x8*)(Vp + (size_t)(di*16 + l15) * NT + kd*32 + quad*8);

        for (int kt = 0; kt < ktend; ++kt) {
            const int kb = kt << 6;

            // S^T = K Q^T : rows = keys (quad*4+r), cols = q-rows (l15)
            f32x4 st[4][2];
#pragma unroll
            for (int ni = 0; ni < 4; ++ni)
#pragma unroll
                for (int mi = 0; mi < 2; ++mi) {
                    st[ni][mi] = 0.0f;
                    st[ni][mi] = mfma16(kf[ni][0], qf[mi][0], st[ni][mi]);
                    st[ni][mi] = mfma16(kf[ni][1], qf[mi][1], st[ni][mi]);
                }

            // prefetch next K tile (hidden under softmax + PV)
            if (kt + 1 < ktend) {
                const int kb2 = kb + 64;
#pragma unroll
                for (int ni = 0; ni < 4; ++ni)
#pragma unroll
                    for (int kd = 0; kd < 2; ++kd)
                        kf[ni][kd] = *(const bf16x8*)(Kp + (size_t)(kb2 + ni*16 + l15) * ND + kd*32 + quad*8);
            }

            // causal mask (straddling tiles only)
            if (kb + 63 > wq0) {
#pragma unroll
                for (int ni = 0; ni < 4; ++ni)
#pragma unroll
                    for (int mi = 0; mi < 2; ++mi) {
                        const int qrow = wq0 + mi*16 + l15;
#pragma unroll
                        for (int r = 0; r < 4; ++r) {
                            const int key = kb + ni*16 + quad*4 + r;
                            if (key > qrow) st[ni][mi][r] = NEG_BIG;
                        }
                    }
            }

            // online softmax: per mi, lane owns one q-row; keys live in regs
#pragma unroll
            for (int mi = 0; mi < 2; ++mi) {
                f32x4 vmax = st[0][mi];
                vmax = vmax4(vmax, st[1][mi]);
                vmax = vmax4(vmax, st[2][mi]);
                vmax = vmax4(vmax, st[3][mi]);
                float nm = fmaxf(fmaxf(vmax[0], vmax[1]), fmaxf(vmax[2], vmax[3]));
                nm = fmaxf(nm, __shfl_xor(nm, 16));
                nm = fmaxf(nm, __shfl_xor(nm, 32));
                const float mnew = fmaxf(m_r[mi], nm);
                const float alpha = fexp2((m_r[mi] - mnew) * LOG2E);
                const float ml = mnew * LOG2E;
                float rs = 0.0f;
#pragma unroll
                for (int ni = 0; ni < 4; ++ni)
#pragma unroll
                    for (int r = 0; r < 4; ++r) {
                        const float e = fexp2(fmaf(st[ni][mi][r], LOG2E, -ml));
                        st[ni][mi][r] = e;
                        rs += e;
                    }
                rs += __shfl_xor(rs, 16);
                rs += __shfl_xor(rs, 32);
                m_r[mi] = mnew;
                l_r[mi] = l_r[mi] * alpha + rs;
#pragma unroll
                for (int di = 0; di < 4; ++di) ot[di][mi] *= alpha;
                // P^T (C-layout) -> pLds as P[q-row][key], 4 keys packed per b64
#pragma unroll
                for (int ni = 0; ni < 4; ++ni) {
                    const f32x4 v = st[ni][mi];
                    *(uint2*)&pLds[mi*16 + l15][ni*16 + quad*4] =
                        make_uint2(pk2(v[0], v[1]), pk2(v[2], v[3]));
                }
            }

            // P^T as B-operand: lane = q-row, regs = keys (contiguous b128)
            bf16x8 pf[2][2];
#pragma unroll
            for (int mi = 0; mi < 2; ++mi)
#pragma unroll
                for (int kd = 0; kd < 2; ++kd)
                    pf[mi][kd] = *(const bf16x8*)&pLds[mi*16 + l15][kd*32 + quad*8];

            // O^T += V^T P^T
#pragma unroll
            for (int di = 0; di < 4; ++di)
#pragma unroll
                for (int mi = 0; mi < 2; ++mi) {
                    ot[di][mi] = mfma16(vf[di][0], pf[mi][0], ot[di][mi]);
                    ot[di][mi] = mfma16(vf[di][1], pf[mi][1], ot[di][mi]);
                }

            // prefetch next V tile
            if (kt + 1 < ktend) {
                const int kb2 = kb + 64;
#pragma unroll
                for (int di = 0; di < 4; ++di)
#pragma unroll
                    for (int kd = 0; kd < 2; ++kd)
                        vf[di][kd] = *(const bf16x8*)(Vp + (size_t)(di*16 + l15) * NT + kb2 + kd*32 + quad*8);
            }
        }

        // epilogue: ctx[b][t=q-row][h*64 + d], d = di*16 + quad*4 + r (packed)
#pragma unroll
        for (int mi = 0; mi < 2; ++mi) {
            const float inv = 1.0f / l_r[mi];
            const int t = wq0 + mi*16 + l15;
            short* dst = ctx + ((size_t)(b * NT + t)) * NC + h*64 + quad*4;
#pragma unroll
            for (int di = 0; di < 4; ++di) {
                const f32x4 v = ot[di][mi] * inv;
                *(uint2*)(dst + di*16) = make_uint2(pk2(v[0], v[1]), pk2(v[2], v[3]));
            }
        }
    }
}

// ---------------------------------------------------------------------------
// GEMM2: out = ctx @ w_out + b_out (fp32 out). ctx bf16, wt bf16 pre-T. BK=64.
// ---------------------------------------------------------------------------
__global__ __launch_bounds__(256)
void out_gemm(const short* __restrict__ a, const short* __restrict__ wt,
              const float* __restrict__ bias, float* __restrict__ out)
{
    __shared__ short aLds[128][72];
    __shared__ short bLds[128][72];
    const int tid  = threadIdx.x;
    const int lane = tid & 63;
    const int wave = tid >> 6;
    const int waveM = wave & 1;
    const int waveN = wave >> 1;
    const int quad = lane >> 4;
    const int l15  = lane & 15;
    const int m0 = blockIdx.x * 128;
    const int n0 = blockIdx.y * 128;

    f32x4 acc[4][4];
#pragma unroll
    for (int i = 0; i < 4; ++i)
#pragma unroll
        for (int j = 0; j < 4; ++j) acc[i][j] = 0.0f;

    const int srow = tid >> 1;
    const int scol = (tid & 1) * 32;

    for (int k0 = 0; k0 < NC; k0 += 64) {
        {
            const short* sa = a + (size_t)(m0 + srow) * NC + k0 + scol;
            *(bf16x8*)&aLds[srow][scol]      = *(const bf16x8*)sa;
            *(bf16x8*)&aLds[srow][scol + 8]  = *(const bf16x8*)(sa + 8);
            *(bf16x8*)&aLds[srow][scol + 16] = *(const bf16x8*)(sa + 16);
            *(bf16x8*)&aLds[srow][scol + 24] = *(const bf16x8*)(sa + 24);
        }
        {
            const short* sb = wt + (size_t)(n0 + srow) * NC + k0 + scol;
            *(bf16x8*)&bLds[srow][scol]      = *(const bf16x8*)sb;
            *(bf16x8*)&bLds[srow][scol + 8]  = *(const bf16x8*)(sb + 8);
            *(bf16x8*)&bLds[srow][scol + 16] = *(const bf16x8*)(sb + 16);
            *(bf16x8*)&bLds[srow][scol + 24] = *(const bf16x8*)(sb + 24);
        }
        __syncthreads();

#pragma unroll
        for (int kd = 0; kd < 2; ++kd) {
            bf16x8 af[4], bfr[4];
#pragma unroll
            for (int mi = 0; mi < 4; ++mi)
                af[mi] = *(const bf16x8*)&aLds[waveM*64 + mi*16 + l15][kd*32 + quad*8];
#pragma unroll
            for (int ni = 0; ni < 4; ++ni)
                bfr[ni] = *(const bf16x8*)&bLds[waveN*64 + ni*16 + l15][kd*32 + quad*8];
#pragma unroll
            for (int mi = 0; mi < 4; ++mi)
#pragma unroll
                for (int ni = 0; ni < 4; ++ni)
                    acc[mi][ni] = mfma16(af[mi], bfr[ni], acc[mi][ni]);
        }
        __syncthreads();
    }

#pragma unroll
    for (int mi = 0; mi < 4; ++mi) {
#pragma unroll
        for (int ni = 0; ni < 4; ++ni) {
            const int n = n0 + waveN*64 + ni*16 + l15;
            const float bb = bias[n];
#pragma unroll
            for (int r = 0; r < 4; ++r) {
                const int m = m0 + waveM*64 + mi*16 + quad*4 + r;
                out[(size_t)m * NC + n] = acc[mi][ni][r] + bb;
            }
        }
    }
}

extern "C" void kernel_launch(void* const* d_in, const int* in_sizes, int n_in,
                              void* d_out, int out_size, void* d_ws, size_t ws_size,
                              hipStream_t stream)
{
    const float* x     = (const float*)d_in[0];
    const float* w_qkv = (const float*)d_in[1];
    const float* b_qkv = (const float*)d_in[2];
    const float* w_out = (const float*)d_in[3];
    const float* b_out = (const float*)d_in[4];
    float* out = (float*)d_out;

    const size_t SZ = (size_t)NB * NH * NT * ND;   // 8.39M elems, 16.8 MB bf16
    short* q   = (short*)d_ws;
    short* kk  = q  + SZ;
    short* vt  = kk + SZ;
    short* ctx = vt + SZ;
    short* xbf = ctx + SZ;   // 5*SZ*2 = 83.9 MB total
    // aliases into dead regions (stream-serial ordering makes this safe):
    short* wTq = ctx;   // live only until attn overwrites ctx (6.3MB < 16.8MB)
    short* wTo = xbf;   // xbf dead after qkv_gemm; wTo used by out_gemm (2MB)

    hipLaunchKernelGGL(xcvt, dim3(BT*NC/(256*8)), dim3(256), 0, stream, x, xbf);
    hipLaunchKernelGGL(transpose_w, dim3(16, 48), dim3(256), 0, stream,
                       w_qkv, wTq, NC, 3*NC);
    hipLaunchKernelGGL(qkv_gemm, dim3(BT/128, (3*NC)/128), dim3(256), 0, stream,
                       xbf, wTq, b_qkv, q, kk, vt);
    hipLaunchKernelGGL(attn, dim3(NB*NH, NT/64), dim3(64), 0, stream,
                       q, kk, vt, ctx);
    hipLaunchKernelGGL(transpose_w, dim3(16, 16), dim3(256), 0, stream,
                       w_out, wTo, NC, NC);
    hipLaunchKernelGGL(out_gemm, dim3(BT/128, NC/128), dim3(256), 0, stream,
                       ctx, wTo, b_out, out);
}